// Round 8
// baseline (208.172 us; speedup 1.0000x reference)
//
#include <hip/hip_runtime.h>

typedef short short8 __attribute__((ext_vector_type(8)));
typedef float f32x4  __attribute__((ext_vector_type(4)));

// Problem dims
constexpr int N_    = 256;
constexpr int T_    = 2048;
constexpr int V_    = 9;
constexpr int FIN_  = 144;      // K dim of stage-1 GEMM
constexpr int J_    = 27;       // output cols (w*3 + o)
constexpr int KT_   = 9;
constexpr int THREADS_ = 256;   // 4 waves
constexpr int TILE_  = 248;     // output rows per block
constexpr int NTILE_ = 9;
constexpr int XSTRIDE_B = 336;              // bf16 row stride (84 words: 2-way banks = free)
constexpr int XBUF_B  = 64 * XSTRIDE_B;     // 21504 B (one 64-row phase tile; also holds Wc at setup)
constexpr int ZSU_    = 28;                 // z row stride in u16 (56B: b32 reads 2-way = free)
constexpr int ZBUF_B  = 256 * ZSU_ * 2;     // 14336 B
constexpr int SMEM_B  = XBUF_B + ZBUF_B;    // 35840 B -> 4 blocks/CU (LDS)

__device__ __forceinline__ unsigned short bf16_rne(float x) {
    unsigned u = __float_as_uint(x);
    u = (u + 0x7FFFu + ((u >> 16) & 1u)) >> 16;
    return (unsigned short)u;
}
__device__ __forceinline__ unsigned pk2(float a, float b) {
    return (unsigned)bf16_rne(a) | ((unsigned)bf16_rne(b) << 16);
}
__device__ __forceinline__ float bflo(unsigned u) { return __uint_as_float(u << 16); }
__device__ __forceinline__ float bfhi(unsigned u) { return __uint_as_float(u & 0xFFFF0000u); }

__global__ __launch_bounds__(THREADS_, 4) void fused_stgcn(const float* __restrict__ pose,
                                                           const float* __restrict__ Ain,
                                                           const float* __restrict__ Wg,
                                                           const float* __restrict__ bg,
                                                           const float* __restrict__ Wt_in,
                                                           const float* __restrict__ bt,
                                                           float* __restrict__ out) {
    __shared__ __align__(16) unsigned char smem[SMEM_B];
    unsigned short* zb = (unsigned short*)(smem + XBUF_B);

    const int tid  = threadIdx.x;
    const int bid  = blockIdx.x;
    const int nb   = bid / NTILE_;
    const int tile = bid % NTILE_;
    const int t0   = tile * TILE_;
    const int lane = tid & 63;
    const int wv   = tid >> 6;
    const int g8   = lane >> 4;
    const int j0   = lane & 15;
    const size_t nrow0 = (size_t)nb * T_;

    // LDS-only barrier: global loads stay in flight across it
    auto WB = []() {
        asm volatile("s_waitcnt lgkmcnt(0)" ::: "memory");
        __builtin_amdgcn_s_barrier();
        asm volatile("" ::: "memory");
    };

    auto issue = [&](int h, float4* ld) {
        #pragma unroll
        for (int q = 0; q < 9; ++q) {
            const int fidx = q * THREADS_ + tid;
            const int r = fidx / 36, c4 = fidx % 36;
            const int text = t0 - 4 + h * 64 + r;
            const bool ok = (text >= 0 && text < T_);
            const float* p = pose + (nrow0 + (size_t)(ok ? text : 0)) * FIN_ + c4 * 4;
            ld[q] = ok ? *(const float4*)p : make_float4(0.f, 0.f, 0.f, 0.f);
        }
    };
    auto stage = [&](const float4* ld) {
        #pragma unroll
        for (int q = 0; q < 9; ++q) {
            const int fidx = q * THREADS_ + tid;
            const int r = fidx / 36, c4 = fidx % 36;
            uint2 u;
            u.x = pk2(ld[q].x, ld[q].y);
            u.y = pk2(ld[q].z, ld[q].w);
            *(uint2*)(smem + r * XSTRIDE_B + c4 * 8) = u;
        }
    };

    float4 ld[9];
    issue(0, ld);                         // first tile's loads overlap the setup compute below

    // ---- Inline setup: Wc[f=(v,c)][j=(w,o)] into LDS (x-region), then B-frags ----
    float* wc = (float*)smem;
    for (int idx = tid; idx < FIN_ * J_; idx += THREADS_) {
        const int f = idx / J_, j = idx % J_;
        const int v = f >> 4, c = f & 15;
        const int w = j / 3, o = j % 3;
        float s = 0.f;
        #pragma unroll
        for (int k = 0; k < 5; ++k)
            s += Wg[(k * 3 + o) * 16 + c] * Ain[(k * 9 + v) * 9 + w];
        wc[idx] = s;
    }
    // per-lane GCN bias B0[n] = sum_k bg[k,o] * sum_v A[k,v,w], n = w*3+o
    float b0n0, b0n1 = 0.f;
    {
        const int n0 = j0, w0 = n0 / 3, o0 = n0 % 3;
        float s0 = 0.f;
        #pragma unroll
        for (int k = 0; k < 5; ++k) {
            float cs = 0.f;
            #pragma unroll
            for (int v = 0; v < V_; ++v) cs += Ain[(k * 9 + v) * 9 + w0];
            s0 += bg[k * 3 + o0] * cs;
        }
        b0n0 = s0;
        if (j0 < 11) {
            const int n1 = 16 + j0, w1 = n1 / 3, o1 = n1 % 3;
            float s1 = 0.f;
            #pragma unroll
            for (int k = 0; k < 5; ++k) {
                float cs = 0.f;
                #pragma unroll
                for (int v = 0; v < V_; ++v) cs += Ain[(k * 9 + v) * 9 + w1];
                s1 += bg[k * 3 + o1] * cs;
            }
            b0n1 = s1;
        }
    }
    WB();   // Wc visible
    // B-frags (16x16x32 bf16): elem e of lane = Wc[k=s*32+g8*8+e][n=nt*16+j0]
    short8 bfrag[5][2];
    #pragma unroll
    for (int s = 0; s < 5; ++s) {
        #pragma unroll
        for (int nt = 0; nt < 2; ++nt) {
            const int n = nt * 16 + j0;
            union { unsigned u[4]; short8 s8; } cvu;
            #pragma unroll
            for (int ep = 0; ep < 4; ++ep) {
                const int k0 = s * 32 + g8 * 8 + ep * 2;
                const float v0 = (k0 < FIN_ && n < J_)     ? wc[k0 * J_ + n]       : 0.f;
                const float v1 = (k0 + 1 < FIN_ && n < J_) ? wc[(k0 + 1) * J_ + n] : 0.f;
                cvu.u[ep] = pk2(v0, v1);
            }
            bfrag[s][nt] = cvu.s8;
        }
    }
    WB();   // Wc reads done; x-region free for staging
    // zero k-pad bytes [288,320) of each staged row (s=4 frag tail reads them)
    for (int i = tid; i < 512; i += THREADS_) {
        const int r = i >> 3, w = i & 7;
        *(float*)(smem + r * XSTRIDE_B + 288 + w * 4) = 0.f;
    }

    // ---- Stage 1: 4 phases x 64 rows; wave wv owns rows [wv*16, wv*16+16) ----
    #pragma unroll 1
    for (int h = 0; h < 4; ++h) {
        stage(ld);                         // waits this phase's vmcnt
        if (h < 3) issue(h + 1, ld);       // refill buffer; in flight across barriers below
        WB();                              // staged tile (and pad zeros on h==0) visible

        const unsigned char* abase = smem + (wv * 16 + j0) * XSTRIDE_B;
        f32x4 acc0 = {0.f, 0.f, 0.f, 0.f};
        f32x4 acc1 = {0.f, 0.f, 0.f, 0.f};
        #pragma unroll
        for (int s = 0; s < 5; ++s) {
            const short8 af = *(const short8*)(abase + s * 64 + g8 * 16);
            acc0 = __builtin_amdgcn_mfma_f32_16x16x32_bf16(af, bfrag[s][0], acc0, 0, 0, 0);
            acc1 = __builtin_amdgcn_mfma_f32_16x16x32_bf16(af, bfrag[s][1], acc1, 0, 0, 0);
        }
        // D layout: col = lane&15, row = g8*4 + reg ; store z as bf16
        #pragma unroll
        for (int r = 0; r < 4; ++r) {
            const int zrow = h * 64 + wv * 16 + g8 * 4 + r;
            const int text = t0 - 4 + zrow;
            const bool okz = (text >= 0 && text < T_);
            zb[zrow * ZSU_ + j0] = bf16_rne(okz ? acc0[r] + b0n0 : 0.f);
            if (j0 < 11)
                zb[zrow * ZSU_ + 16 + j0] = bf16_rne(okz ? acc1[r] + b0n1 : 0.f);
        }
        WB();                              // frag reads + z writes done before next stage()
    }

    // ---- Stage 2: temporal 9-tap mix + bias + leaky relu ----
    const int rows_out = min(TILE_, T_ - t0);
    float oacc[J_];
    if (tid < rows_out) {
        #pragma unroll
        for (int w = 0; w < V_; ++w)
            #pragma unroll
            for (int o2 = 0; o2 < 3; ++o2)
                oacc[w * 3 + o2] = bt[o2];
        #pragma unroll
        for (int dd = 0; dd < KT_; ++dd) {
            const unsigned* zp = (const unsigned*)(zb + (tid + dd) * ZSU_);
            float zf[28];
            #pragma unroll
            for (int c = 0; c < 14; ++c) {
                const unsigned u = zp[c];
                zf[2 * c]     = bflo(u);
                zf[2 * c + 1] = bfhi(u);
            }
            #pragma unroll
            for (int o = 0; o < 3; ++o) {
                #pragma unroll
                for (int o2 = 0; o2 < 3; ++o2) {
                    const float wt = Wt_in[(o2 * 3 + o) * KT_ + (KT_ - 1 - dd)];
                    #pragma unroll
                    for (int w = 0; w < V_; ++w)
                        oacc[w * 3 + o2] = fmaf(zf[w * 3 + o], wt, oacc[w * 3 + o2]);
                }
            }
        }
        #pragma unroll
        for (int j = 0; j < J_; ++j) oacc[j] = fmaxf(oacc[j], 0.01f * oacc[j]);
    }
    WB();   // stage-2 reads of zb complete
    // repack tight f32 (stride 27) into smem base for coalesced store (26784B <= 35840B)
    float* rp = (float*)smem;
    if (tid < rows_out) {
        #pragma unroll
        for (int j = 0; j < J_; ++j) rp[tid * J_ + j] = oacc[j];
    }
    WB();   // repack visible

    const int total4 = (rows_out * J_) / 4;   // 1674 or 432
    float4* dst4 = (float4*)(out + (nrow0 + t0) * J_);
    const float4* src4 = (const float4*)rp;
    for (int idx = tid; idx < total4; idx += THREADS_)
        dst4[idx] = src4[idx];
}

extern "C" void kernel_launch(void* const* d_in, const int* in_sizes, int n_in,
                              void* d_out, int out_size, void* d_ws, size_t ws_size,
                              hipStream_t stream) {
    const float* pose = (const float*)d_in[0];
    const float* A    = (const float*)d_in[1];
    const float* Wg   = (const float*)d_in[2];
    const float* bg   = (const float*)d_in[3];
    const float* Wt   = (const float*)d_in[4];
    const float* bt   = (const float*)d_in[5];
    float* outp = (float*)d_out;

    fused_stgcn<<<N_ * NTILE_, THREADS_, 0, stream>>>(pose, A, Wg, bg, Wt, bt, outp);
}

// Round 9
// 109.167 us; speedup vs baseline: 1.9069x; 1.9069x over previous
//
#include <hip/hip_runtime.h>

typedef short short8 __attribute__((ext_vector_type(8)));
typedef float f32x4  __attribute__((ext_vector_type(4)));

// Problem dims
constexpr int N_    = 256;
constexpr int T_    = 2048;
constexpr int V_    = 9;
constexpr int FIN_  = 144;      // K dim of stage-1 GEMM
constexpr int J_    = 27;       // output cols (w*3 + o)
constexpr int KT_   = 9;
constexpr int ZPS_  = 28;       // z row stride in u16 (padded 27->28)
constexpr int TT_   = N_ * T_ / 16;   // 32768 M-tiles of 16 rows
constexpr int K1B_  = 1024;           // K1 blocks (4 waves each)
constexpr int K1W_  = K1B_ * 4;       // 4096 waves; each does 8 tiles
constexpr int TILE2_ = 248;           // K2 output rows per block
constexpr int NT2_   = 9;

// ws layout: floats [0..2560) B-frags (5120 bf16), [2560..2587) B0; z bf16 at float-offset 4096
constexpr int BF_OFF_F  = 0;
constexpr int B0_OFF    = 2560;
constexpr int ZWS_OFF_F = 4096;   // byte 16384; z needs 256*2048*28*2 = 29.4 MB of ws

__device__ __forceinline__ unsigned short bf16_rne(float x) {
    unsigned u = __float_as_uint(x);
    u = (u + 0x7FFFu + ((u >> 16) & 1u)) >> 16;
    return (unsigned short)u;
}
__device__ __forceinline__ unsigned pk2(float a, float b) {
    return (unsigned)bf16_rne(a) | ((unsigned)bf16_rne(b) << 16);
}
__device__ __forceinline__ float bflo(unsigned u) { return __uint_as_float(u << 16); }
__device__ __forceinline__ float bfhi(unsigned u) { return __uint_as_float(u & 0xFFFF0000u); }

__global__ void setup_weights(const float* __restrict__ A,
                              const float* __restrict__ Wg,
                              const float* __restrict__ bg,
                              float* __restrict__ ws) {
    __shared__ float Wc[FIN_ * J_];   // [k=f][n=j]
    const int tid = threadIdx.x;
    for (int idx = tid; idx < FIN_ * J_; idx += 256) {
        const int f = idx / J_, j = idx % J_;
        const int v = f >> 4, c = f & 15;
        const int w = j / 3, o = j % 3;
        float s = 0.f;
        #pragma unroll
        for (int k = 0; k < 5; ++k)
            s += Wg[(k * 3 + o) * 16 + c] * A[(k * 9 + v) * 9 + w];
        Wc[idx] = s;
    }
    __syncthreads();
    // B-frags for mfma_f32_16x16x32_bf16: elem e of lane: (k=s*32+(l>>4)*8+e, n=nt*16+(l&15))
    unsigned short* bfp = (unsigned short*)(ws + BF_OFF_F);
    for (int i = tid; i < 5120; i += 256) {
        const int e = i & 7, lane = (i >> 3) & 63, nt = (i >> 9) & 1, s = i >> 10;
        const int k = s * 32 + (lane >> 4) * 8 + e;
        const int n = nt * 16 + (lane & 15);
        const float val = (k < FIN_ && n < J_) ? Wc[k * J_ + n] : 0.f;
        bfp[i] = bf16_rne(val);
    }
    if (tid < J_) {
        const int w = tid / 3, o = tid % 3;
        float s = 0.f;
        #pragma unroll
        for (int k = 0; k < 5; ++k) {
            float cs = 0.f;
            #pragma unroll
            for (int v = 0; v < V_; ++v) cs += A[(k * 9 + v) * 9 + w];
            s += bg[k * 3 + o] * cs;
        }
        ws[B0_OFF + tid] = s;
    }
}

// ---------------- K1: pure-streaming GEMM, no LDS, no barriers ----------------
__global__ __launch_bounds__(256) void k1_gemm(const float* __restrict__ pose,
                                               const float* __restrict__ cw,
                                               unsigned short* __restrict__ zg) {
    const int tid  = threadIdx.x;
    const int lane = tid & 63;
    const int wv   = tid >> 6;
    const int g8   = lane >> 4;
    const int j0   = lane & 15;
    const int wgid = blockIdx.x * 4 + wv;   // 0..4095

    short8 bfrag[5][2];
    {
        const short8* bsrc = (const short8*)(cw + BF_OFF_F);
        #pragma unroll
        for (int s = 0; s < 5; ++s)
            #pragma unroll
            for (int nt = 0; nt < 2; ++nt)
                bfrag[s][nt] = bsrc[(s * 2 + nt) * 64 + lane];
    }
    const float b0n0 = cw[B0_OFF + j0];
    const float b0n1 = (j0 < 11) ? cw[B0_OFF + 16 + j0] : 0.f;

    auto issue = [&](int t16, float4* Av, float4* Bv) {
        const int nb = t16 >> 7;
        const int tr = (t16 & 127) << 4;
        const float* rowp = pose + ((size_t)nb * T_ + tr + j0) * FIN_;
        #pragma unroll
        for (int s = 0; s < 5; ++s) {
            int k0 = s * 32 + g8 * 8;
            if (k0 > 136) k0 = 128;   // K-tail: B-frag is zero there, A values irrelevant
            Av[s] = *(const float4*)(rowp + k0);
            Bv[s] = *(const float4*)(rowp + k0 + 4);
        }
    };
    auto process = [&](int t16, const float4* Av, const float4* Bv) {
        short8 af[5];
        #pragma unroll
        for (int s = 0; s < 5; ++s) {
            union { unsigned u[4]; short8 s8; } cvu;
            cvu.u[0] = pk2(Av[s].x, Av[s].y);
            cvu.u[1] = pk2(Av[s].z, Av[s].w);
            cvu.u[2] = pk2(Bv[s].x, Bv[s].y);
            cvu.u[3] = pk2(Bv[s].z, Bv[s].w);
            af[s] = cvu.s8;
        }
        f32x4 acc0 = {0.f, 0.f, 0.f, 0.f};
        f32x4 acc1 = {0.f, 0.f, 0.f, 0.f};
        #pragma unroll
        for (int s = 0; s < 5; ++s) {
            acc0 = __builtin_amdgcn_mfma_f32_16x16x32_bf16(af[s], bfrag[s][0], acc0, 0, 0, 0);
            acc1 = __builtin_amdgcn_mfma_f32_16x16x32_bf16(af[s], bfrag[s][1], acc1, 0, 0, 0);
        }
        const int nb = t16 >> 7;
        const int tr = (t16 & 127) << 4;
        unsigned short* zr = zg + ((size_t)nb * T_ + tr) * ZPS_;
        // D layout: col = lane&15, row = g8*4 + r
        #pragma unroll
        for (int r = 0; r < 4; ++r) {
            unsigned short* p = zr + (g8 * 4 + r) * ZPS_;
            p[j0] = bf16_rne(acc0[r] + b0n0);
            if (j0 < 11) p[16 + j0] = bf16_rne(acc1[r] + b0n1);
        }
    };

    float4 Aa[5], Ba[5], Ab[5], Bb[5];
    issue(wgid, Aa, Ba);
    #pragma unroll 1
    for (int i = 0; i < 8; i += 2) {            // TT_/K1W_ = 8 tiles per wave, exact
        const int t = wgid + i * K1W_;
        issue(t + K1W_, Ab, Bb);
        process(t, Aa, Ba);
        if (i < 6) issue(t + 2 * K1W_, Aa, Ba);
        process(t + K1W_, Ab, Bb);
    }
}

// ---------------- K2: temporal 9-tap conv + bias + leaky relu ----------------
__global__ __launch_bounds__(256) void k2_tcn(const unsigned short* __restrict__ zg,
                                              const float* __restrict__ Wt_in,
                                              const float* __restrict__ bt,
                                              float* __restrict__ out) {
    __shared__ __align__(16) float zb[256 * ZPS_];   // 28672 B; stride 28 f32 = conflict-free-min b128

    const int tid  = threadIdx.x;
    const int bid  = blockIdx.x;
    const int nb   = bid / NT2_;
    const int tile = bid % NT2_;
    const int t0   = tile * TILE2_;

    // coalesced dword loads of z rows [t0-4, t0+252), unpack bf16 -> f32 LDS
    const unsigned* zg32 = (const unsigned*)zg;
    #pragma unroll
    for (int q = 0; q < 14; ++q) {
        const int d  = q * 256 + tid;        // 3584 dwords = 256 rows * 14
        const int rl = d / 14, c2 = d % 14;
        const int row = t0 - 4 + rl;
        const bool ok = (row >= 0 && row < T_);
        const unsigned u = ok ? zg32[((size_t)nb * T_ + row) * (ZPS_ / 2) + c2] : 0u;
        float2 f;
        f.x = bflo(u);
        f.y = bfhi(u);
        *(float2*)&zb[2 * d] = f;            // byte addr = 8*d: perfectly sequential
    }
    __syncthreads();

    const int rows_out = min(TILE2_, T_ - t0);
    float oacc[J_];
    if (tid < rows_out) {
        #pragma unroll
        for (int w = 0; w < V_; ++w)
            #pragma unroll
            for (int o2 = 0; o2 < 3; ++o2)
                oacc[w * 3 + o2] = bt[o2];
        #pragma unroll
        for (int dd = 0; dd < KT_; ++dd) {
            union { f32x4 v4[7]; float f[28]; } zu;
            const f32x4* zp = (const f32x4*)&zb[(tid + dd) * ZPS_];
            #pragma unroll
            for (int c = 0; c < 7; ++c) zu.v4[c] = zp[c];
            #pragma unroll
            for (int o = 0; o < 3; ++o) {
                #pragma unroll
                for (int o2 = 0; o2 < 3; ++o2) {
                    const float wt = Wt_in[(o2 * 3 + o) * KT_ + (KT_ - 1 - dd)];
                    #pragma unroll
                    for (int w = 0; w < V_; ++w)
                        oacc[w * 3 + o2] = fmaf(zu.f[w * 3 + o], wt, oacc[w * 3 + o2]);
                }
            }
        }
        #pragma unroll
        for (int j = 0; j < J_; ++j) oacc[j] = fmaxf(oacc[j], 0.01f * oacc[j]);
    }
    __syncthreads();
    // repack tight (stride 27) into zb for coalesced store (26784 B <= 28672 B)
    if (tid < rows_out) {
        #pragma unroll
        for (int j = 0; j < J_; ++j) zb[tid * J_ + j] = oacc[j];
    }
    __syncthreads();

    const int total4 = (rows_out * J_) / 4;   // 1674 or 432
    float4* dst4 = (float4*)(out + ((size_t)nb * T_ + t0) * J_);
    const float4* src4 = (const float4*)zb;
    for (int idx = tid; idx < total4; idx += 256)
        dst4[idx] = src4[idx];
}

extern "C" void kernel_launch(void* const* d_in, const int* in_sizes, int n_in,
                              void* d_out, int out_size, void* d_ws, size_t ws_size,
                              hipStream_t stream) {
    const float* pose = (const float*)d_in[0];
    const float* A    = (const float*)d_in[1];
    const float* Wg   = (const float*)d_in[2];
    const float* bg   = (const float*)d_in[3];
    const float* Wt   = (const float*)d_in[4];
    const float* bt   = (const float*)d_in[5];
    float* ws   = (float*)d_ws;
    unsigned short* zg = (unsigned short*)(ws + ZWS_OFF_F);
    float* outp = (float*)d_out;

    setup_weights<<<1, 256, 0, stream>>>(A, Wg, bg, ws);
    k1_gemm<<<K1B_, 256, 0, stream>>>(pose, ws, zg);
    k2_tcn<<<N_ * NT2_, 256, 0, stream>>>(zg, Wt, bt, outp);
}